// Round 1
// baseline (722.686 us; speedup 1.0000x reference)
//
#include <hip/hip_runtime.h>

// POMO decoder: B=64, N=500, E=128, H=8, D=16. All fp32.
// Pipeline:
//   K1 gemm_xw : q  = encF*WqF^T + encL*WqL^T            -> ws_q  [32000,128]
//   K2 gemm_xw : kv = encN*[Wk;Wv]^T                     -> ws_kv [32000,256]
//   K3 attn    : att[b,n,h*16+d] = softmax(qk/4+mask)*v  -> ws_att[32000,128]
//   K4 gemm_xw : mh = att*Wc^T + bc                      -> ws_mh (reuses ws_q)
//   K5 pointer : p = exp(10*tanh(mh*enc^T/sqrt128)+mask) -> d_out (unnormalized), rowsums -> ws_rsum
//   K6 norm    : d_out /= rowsum
// Softmax max-subtraction is skipped: attention logits ~N(0,1.4) (no overflow),
// pointer logits clipped to [-10,10]; exp(-1e9) underflows to exactly 0.

#define B_ 64
#define N_ 500

__device__ __forceinline__ float4 ld4(const float* p) { return *reinterpret_cast<const float4*>(p); }
__device__ __forceinline__ void st4(float* p, const float4 v) { *reinterpret_cast<float4*>(p) = v; }

__device__ __forceinline__ float fast_tanh(float x) {
    // 1 - 2/(e^{2x}+1); exact at +-inf, ~1e-7 abs err near 0 (fine for probs).
    const float e = __expf(2.f * x);
    return 1.f - 2.f / (e + 1.f);
}

// C[M,F] = sum_t A_t * W_t^T (+bias). M=32000, K=128 fixed. F in {128,256}.
// W row f uses Wa when global f<128 else Wb (for the stacked [Wk;Wv] case).
// Tiles: 64x64 per block, per-thread 4x4, BK=16, transposed LDS tiles (stride 68).
__global__ __launch_bounds__(256) void gemm_xw(
    const float* __restrict__ A1, const float* __restrict__ W1a, const float* __restrict__ W1b,
    const float* __restrict__ A2, const float* __restrict__ W2a, const float* __restrict__ W2b,
    const float* __restrict__ bias, float* __restrict__ C, const int F, const int nterm)
{
    __shared__ __align__(16) float At[16][68];
    __shared__ __align__(16) float Wt[16][68];
    const int t = threadIdx.x;
    const int rb = blockIdx.y * 64;
    const int fb = blockIdx.x * 64;
    const int r0 = (t >> 4) * 4;   // thread row base within tile
    const int f0 = (t & 15) * 4;   // thread col base within tile
    const int srow = t >> 2;       // staging row 0..63
    const int sde  = (t & 3) * 4;  // staging k-offset 0,4,8,12

    float acc[4][4];
#pragma unroll
    for (int i = 0; i < 4; ++i)
#pragma unroll
        for (int j = 0; j < 4; ++j) acc[i][j] = 0.f;

    for (int tt = 0; tt < nterm; ++tt) {
        const float* A  = tt ? A2 : A1;
        const float* Wa = tt ? W2a : W1a;
        const float* Wb = tt ? W2b : W1b;
        const float* W  = (fb < 128) ? Wa : Wb;
        const int fr = (fb & 127) + srow;
        for (int e0 = 0; e0 < 128; e0 += 16) {
            __syncthreads();
            const float4 av = ld4(&A[(size_t)(rb + srow) * 128 + e0 + sde]);
            At[sde + 0][srow] = av.x; At[sde + 1][srow] = av.y;
            At[sde + 2][srow] = av.z; At[sde + 3][srow] = av.w;
            const float4 wv = ld4(&W[(size_t)fr * 128 + e0 + sde]);
            Wt[sde + 0][srow] = wv.x; Wt[sde + 1][srow] = wv.y;
            Wt[sde + 2][srow] = wv.z; Wt[sde + 3][srow] = wv.w;
            __syncthreads();
#pragma unroll
            for (int d = 0; d < 16; ++d) {
                const float4 a4 = ld4(&At[d][r0]);
                const float4 w4 = ld4(&Wt[d][f0]);
                const float a[4] = {a4.x, a4.y, a4.z, a4.w};
                const float w[4] = {w4.x, w4.y, w4.z, w4.w};
#pragma unroll
                for (int i = 0; i < 4; ++i)
#pragma unroll
                    for (int j = 0; j < 4; ++j) acc[i][j] += a[i] * w[j];
            }
        }
    }

    float4 bv = make_float4(0.f, 0.f, 0.f, 0.f);
    if (bias) bv = ld4(&bias[fb + f0]);
#pragma unroll
    for (int i = 0; i < 4; ++i) {
        float4 o;
        o.x = acc[i][0] + bv.x; o.y = acc[i][1] + bv.y;
        o.z = acc[i][2] + bv.z; o.w = acc[i][3] + bv.w;
        st4(&C[(size_t)(rb + r0 + i) * F + fb + f0], o);
    }
}

// Attention per (row-tile, h, b). j-chunks of 64; no max pass (see header).
__global__ __launch_bounds__(256) void attn_kernel(
    const float* __restrict__ q, const float* __restrict__ kv,
    const float* __restrict__ mask, float* __restrict__ att)
{
    __shared__ __align__(16) float Qt[16][68];  // [d][row]
    __shared__ __align__(16) float Kt[16][68];  // [d][j]
    __shared__ __align__(16) float Vs[64][16];  // [j][d]
    const int t = threadIdx.x;
    const int rt = blockIdx.x;
    const int h  = blockIdx.y;
    const int b  = blockIdx.z;
    const int tj = t & 15;
    const int r0 = (t >> 4) * 4;
    const int j0 = tj * 4;
    const int srow = t >> 2;
    const int sde  = (t & 3) * 4;

    {
        int rg = rt * 64 + srow; if (rg > 499) rg = 499;
        const float4 qa = ld4(&q[((size_t)(b * N_ + rg)) * 128 + h * 16 + sde]);
        Qt[sde + 0][srow] = qa.x; Qt[sde + 1][srow] = qa.y;
        Qt[sde + 2][srow] = qa.z; Qt[sde + 3][srow] = qa.w;
    }

    float out[4][16];
#pragma unroll
    for (int i = 0; i < 4; ++i)
#pragma unroll
        for (int d = 0; d < 16; ++d) out[i][d] = 0.f;
    float sum[4] = {0.f, 0.f, 0.f, 0.f};

    for (int jc = 0; jc < 8; ++jc) {
        __syncthreads();
        {
            int jg = jc * 64 + srow; if (jg > 499) jg = 499;
            const float* kp = &kv[((size_t)(b * N_ + jg)) * 256 + h * 16];
            const float4 ka = ld4(kp + sde);
            Kt[sde + 0][srow] = ka.x; Kt[sde + 1][srow] = ka.y;
            Kt[sde + 2][srow] = ka.z; Kt[sde + 3][srow] = ka.w;
            const float4 va = ld4(kp + 128 + sde);
            st4(&Vs[srow][sde], va);
        }
        __syncthreads();

        float s[4][4];
#pragma unroll
        for (int i = 0; i < 4; ++i)
#pragma unroll
            for (int j = 0; j < 4; ++j) s[i][j] = 0.f;
#pragma unroll
        for (int d = 0; d < 16; ++d) {
            const float4 a4 = ld4(&Qt[d][r0]);
            const float4 k4 = ld4(&Kt[d][j0]);
            const float a[4] = {a4.x, a4.y, a4.z, a4.w};
            const float k[4] = {k4.x, k4.y, k4.z, k4.w};
#pragma unroll
            for (int i = 0; i < 4; ++i)
#pragma unroll
                for (int j = 0; j < 4; ++j) s[i][j] += a[i] * k[j];
        }

        float p[4][4];
#pragma unroll
        for (int i = 0; i < 4; ++i) {
            const int rg = rt * 64 + r0 + i;
            const int gg = jc * 64 + j0;
            float4 mv;
            if (rg < 500 && gg < 500) mv = ld4(&mask[((size_t)b * N_ + rg) * N_ + gg]);
            else mv = make_float4(-1e9f, -1e9f, -1e9f, -1e9f);
            p[i][0] = __expf(s[i][0] * 0.25f + mv.x);
            p[i][1] = __expf(s[i][1] * 0.25f + mv.y);
            p[i][2] = __expf(s[i][2] * 0.25f + mv.z);
            p[i][3] = __expf(s[i][3] * 0.25f + mv.w);
            sum[i] += p[i][0] + p[i][1] + p[i][2] + p[i][3];
        }

#pragma unroll
        for (int jj = 0; jj < 4; ++jj) {
            const float* vp = &Vs[j0 + jj][0];
            const float4 v0 = ld4(vp + 0), v1 = ld4(vp + 4), v2 = ld4(vp + 8), v3 = ld4(vp + 12);
            const float vv[16] = {v0.x, v0.y, v0.z, v0.w, v1.x, v1.y, v1.z, v1.w,
                                  v2.x, v2.y, v2.z, v2.w, v3.x, v3.y, v3.z, v3.w};
#pragma unroll
            for (int i = 0; i < 4; ++i) {
                const float pij = p[i][jj];
#pragma unroll
                for (int d = 0; d < 16; ++d) out[i][d] += pij * vv[d];
            }
        }
    }

    // reduce over the 16 tj lanes (same tr group; xor masks stay in-group)
#pragma unroll
    for (int m = 1; m < 16; m <<= 1) {
#pragma unroll
        for (int i = 0; i < 4; ++i) {
            sum[i] += __shfl_xor(sum[i], m, 64);
#pragma unroll
            for (int d = 0; d < 16; ++d) out[i][d] += __shfl_xor(out[i][d], m, 64);
        }
    }

#pragma unroll
    for (int i = 0; i < 4; ++i) {
        const int rg = rt * 64 + r0 + i;
        if (rg < 500) {
            float val = out[i][0];
#pragma unroll
            for (int d = 1; d < 16; ++d) val = (tj == d) ? out[i][d] : val;  // branchless select
            att[((size_t)(b * N_ + rg)) * 128 + h * 16 + tj] = val / sum[i];
        }
    }
}

// Pointer logits: s = mh*enc^T/sqrt(128); p = exp(10*tanh(s)+mask) stored
// unnormalized to d_out; per-row sums to rsum.
__global__ __launch_bounds__(256) void pointer_kernel(
    const float* __restrict__ mh, const float* __restrict__ enc,
    const float* __restrict__ mask, float* __restrict__ outp, float* __restrict__ rsum)
{
    __shared__ __align__(16) float Mt[16][68];  // [e][row]
    __shared__ __align__(16) float Et[16][68];  // [e][g]
    const int t = threadIdx.x;
    const int rt = blockIdx.x;
    const int b  = blockIdx.y;
    const int tj = t & 15;
    const int r0 = (t >> 4) * 4;
    const int g0 = tj * 4;
    const int srow = t >> 2;
    const int sde  = (t & 3) * 4;

    int rgl = rt * 64 + srow; if (rgl > 499) rgl = 499;
    float rs[4] = {0.f, 0.f, 0.f, 0.f};

    for (int gc = 0; gc < 8; ++gc) {
        float s[4][4];
#pragma unroll
        for (int i = 0; i < 4; ++i)
#pragma unroll
            for (int j = 0; j < 4; ++j) s[i][j] = 0.f;

        for (int ec = 0; ec < 8; ++ec) {
            __syncthreads();
            const float4 mv4 = ld4(&mh[((size_t)(b * N_ + rgl)) * 128 + ec * 16 + sde]);
            Mt[sde + 0][srow] = mv4.x; Mt[sde + 1][srow] = mv4.y;
            Mt[sde + 2][srow] = mv4.z; Mt[sde + 3][srow] = mv4.w;
            int gg = gc * 64 + srow; if (gg > 499) gg = 499;
            const float4 ev = ld4(&enc[((size_t)(b * N_ + gg)) * 128 + ec * 16 + sde]);
            Et[sde + 0][srow] = ev.x; Et[sde + 1][srow] = ev.y;
            Et[sde + 2][srow] = ev.z; Et[sde + 3][srow] = ev.w;
            __syncthreads();
#pragma unroll
            for (int d = 0; d < 16; ++d) {
                const float4 a4 = ld4(&Mt[d][r0]);
                const float4 e4 = ld4(&Et[d][g0]);
                const float a[4] = {a4.x, a4.y, a4.z, a4.w};
                const float e[4] = {e4.x, e4.y, e4.z, e4.w};
#pragma unroll
                for (int i = 0; i < 4; ++i)
#pragma unroll
                    for (int j = 0; j < 4; ++j) s[i][j] += a[i] * e[j];
            }
        }

#pragma unroll
        for (int i = 0; i < 4; ++i) {
            const int rg = rt * 64 + r0 + i;
            const int gg = gc * 64 + g0;
            const bool ok = (rg < 500) && (gg < 500);
            float4 mv;
            if (ok) mv = ld4(&mask[((size_t)b * N_ + rg) * N_ + gg]);
            else mv = make_float4(-1e9f, -1e9f, -1e9f, -1e9f);
            const float c = 0.08838834764831845f;  // 1/sqrt(128)
            float4 pv;
            pv.x = __expf(10.f * fast_tanh(s[i][0] * c) + mv.x);
            pv.y = __expf(10.f * fast_tanh(s[i][1] * c) + mv.y);
            pv.z = __expf(10.f * fast_tanh(s[i][2] * c) + mv.z);
            pv.w = __expf(10.f * fast_tanh(s[i][3] * c) + mv.w);
            rs[i] += pv.x + pv.y + pv.z + pv.w;
            if (ok) st4(&outp[((size_t)b * N_ + rg) * N_ + gg], pv);
        }
    }

#pragma unroll
    for (int m = 1; m < 16; m <<= 1)
#pragma unroll
        for (int i = 0; i < 4; ++i) rs[i] += __shfl_xor(rs[i], m, 64);
    if (tj == 0) {
#pragma unroll
        for (int i = 0; i < 4; ++i) {
            const int rg = rt * 64 + r0 + i;
            if (rg < 500) rsum[b * 512 + rg] = rs[i];
        }
    }
}

__global__ __launch_bounds__(128) void norm_kernel(
    float* __restrict__ outp, const float* __restrict__ rsum)
{
    const int row = blockIdx.x;  // 0..31999
    const int t = threadIdx.x;
    if (t < 125) {
        const int b = row / 500;
        const int n = row - b * 500;
        const float inv = 1.f / rsum[b * 512 + n];
        const size_t off = (size_t)row * 500 + t * 4;
        float4 v = ld4(&outp[off]);
        v.x *= inv; v.y *= inv; v.z *= inv; v.w *= inv;
        st4(&outp[off], v);
    }
}

extern "C" void kernel_launch(void* const* d_in, const int* in_sizes, int n_in,
                              void* d_out, int out_size, void* d_ws, size_t ws_size,
                              hipStream_t stream) {
    const float* enc  = (const float*)d_in[0];
    const float* encf = (const float*)d_in[1];
    const float* encl = (const float*)d_in[2];
    const float* mask = (const float*)d_in[3];
    const float* Wqf  = (const float*)d_in[4];
    const float* Wql  = (const float*)d_in[5];
    const float* Wk   = (const float*)d_in[6];
    const float* Wv   = (const float*)d_in[7];
    const float* Wc   = (const float*)d_in[8];
    const float* bc   = (const float*)d_in[9];
    float* out = (float*)d_out;
    float* ws = (float*)d_ws;

    float* ws_q    = ws;              // 4,096,000 floats
    float* ws_kv   = ws + 4096000;    // 8,192,000 floats
    float* ws_att  = ws + 12288000;   // 4,096,000 floats
    float* ws_mh   = ws_q;            // q dead after attn
    float* ws_rsum = ws_kv;           // kv dead after attn (64*512 floats)

    // K1: q = encF*WqF^T + encL*WqL^T
    gemm_xw<<<dim3(2, 500), 256, 0, stream>>>(encf, Wqf, nullptr, encl, Wql, nullptr,
                                              nullptr, ws_q, 128, 2);
    // K2: kv = encN*[Wk;Wv]^T
    gemm_xw<<<dim3(4, 500), 256, 0, stream>>>(enc, Wk, Wv, nullptr, nullptr, nullptr,
                                              nullptr, ws_kv, 256, 1);
    // K3: attention
    attn_kernel<<<dim3(8, 8, 64), 256, 0, stream>>>(ws_q, ws_kv, mask, ws_att);
    // K4: mh = att*Wc^T + bc
    gemm_xw<<<dim3(2, 500), 256, 0, stream>>>(ws_att, Wc, nullptr, nullptr, nullptr, nullptr,
                                              bc, ws_mh, 128, 1);
    // K5: pointer logits -> unnormalized probs + row sums
    pointer_kernel<<<dim3(8, 64), 256, 0, stream>>>(ws_mh, enc, mask, out, ws_rsum);
    // K6: normalize
    norm_kernel<<<32000, 128, 0, stream>>>(out, ws_rsum);
}